// Round 1
// baseline (4195.280 us; speedup 1.0000x reference)
//
#include <hip/hip_runtime.h>
#include <hip/hip_bf16.h>
#include <cstdint>

// Problem constants
#define TT   2048
#define CC   1024
#define NHH  16
#define HDD  64
#define EE   8
#define HIDD 4096
#define ROWCAP 4608   // 4096 token-expert rows + 8*64 padding, multiple of 64
#define EPSF 1e-6f

// ---------------------------------------------------------------------------
// init: zero counters, mark all dispatch rows as padding (-1)
__global__ void init_kernel(int* rowtok, int* cnt, float* psum, float* argc) {
    int g = blockIdx.x * 256 + threadIdx.x;
    if (g < ROWCAP) rowtok[g] = -1;
    if (g < EE) { cnt[g] = 0; psum[g] = 0.f; argc[g] = 0.f; }
}

// ---------------------------------------------------------------------------
// RMSNorm: one block per row
__global__ void rmsnorm_kernel(const float* __restrict__ x,
                               const float* __restrict__ w,
                               float* __restrict__ out) {
    int t = blockIdx.x, tid = threadIdx.x;
    __shared__ float red[256];
    const float* xr = x + (size_t)t * CC;
    float ss = 0.f;
    for (int c = tid; c < CC; c += 256) { float v = xr[c]; ss += v * v; }
    red[tid] = ss; __syncthreads();
    for (int s = 128; s > 0; s >>= 1) {
        if (tid < s) red[tid] += red[tid + s];
        __syncthreads();
    }
    float inv = rsqrtf(red[0] * (1.0f / CC) + EPSF);
    float* orow = out + (size_t)t * CC;
    for (int c = tid; c < CC; c += 256) orow[c] = xr[c] * inv * w[c];
}

// ---------------------------------------------------------------------------
// Generic fp32 GEMM: C = A[MxK] @ B[KxN] (+ res), 64x64 tile, 4x4 per thread
__global__ __launch_bounds__(256)
void gemm64(const float* __restrict__ A, const float* __restrict__ B,
            float* __restrict__ Cmat, const float* __restrict__ res,
            int M, int N, int Kd) {
    __shared__ float As[16][65];
    __shared__ float Bs[16][64];
    int tid = threadIdx.x;
    int m0 = blockIdx.x * 64, n0 = blockIdx.y * 64;
    int ai = tid >> 2, ak4 = (tid & 3) * 4;
    int bk = tid >> 4, bj4 = (tid & 15) * 4;
    int ty = tid >> 4, tx = tid & 15;
    float acc[4][4] = {};
    for (int k0 = 0; k0 < Kd; k0 += 16) {
        float4 av = *(const float4*)(A + (size_t)(m0 + ai) * Kd + k0 + ak4);
        As[ak4 + 0][ai] = av.x; As[ak4 + 1][ai] = av.y;
        As[ak4 + 2][ai] = av.z; As[ak4 + 3][ai] = av.w;
        *(float4*)&Bs[bk][bj4] = *(const float4*)(B + (size_t)(k0 + bk) * N + n0 + bj4);
        __syncthreads();
#pragma unroll
        for (int kk = 0; kk < 16; kk++) {
            float a[4], b[4];
#pragma unroll
            for (int r = 0; r < 4; r++) a[r] = As[kk][ty * 4 + r];
#pragma unroll
            for (int c = 0; c < 4; c++) b[c] = Bs[kk][tx * 4 + c];
#pragma unroll
            for (int r = 0; r < 4; r++)
#pragma unroll
                for (int c = 0; c < 4; c++) acc[r][c] += a[r] * b[c];
        }
        __syncthreads();
    }
#pragma unroll
    for (int r = 0; r < 4; r++) {
        size_t row = m0 + ty * 4 + r;
#pragma unroll
        for (int c = 0; c < 4; c++) {
            size_t idx = row * N + n0 + tx * 4 + c;
            float v = acc[r][c];
            if (res) v += res[idx];
            Cmat[idx] = v;
        }
    }
}

// ---------------------------------------------------------------------------
// RoPE in-place on [T, NH*HD] buffer. One wave handles 2 heads (64 lanes =
// 2 x 32 pairs); loads complete before stores within the lockstep wave, so
// in-place is safe.
__global__ void rope_kernel(float* buf) {
    int lane = threadIdx.x;
    int fh = blockIdx.x * 2 + (lane >> 5);   // flat head = t*NH + h
    int i = lane & 31;
    int t = fh >> 4;                          // NH = 16
    size_t base = (size_t)fh * HDD;
    float v0 = buf[base + 2 * i];
    float v1 = buf[base + 2 * i + 1];
    float freq = powf(10000.f, -(float)i / 32.f);
    float ang = (float)t * freq;
    float sn, cs;
    sincosf(ang, &sn, &cs);
    buf[base + i]      = v0 * cs - v1 * sn;
    buf[base + 32 + i] = v0 * sn + v1 * cs;
}

// ---------------------------------------------------------------------------
// Causal attention, one block per (query t, head). Scores kept in LDS.
__global__ __launch_bounds__(256)
void attn_kernel(const float* __restrict__ q, const float* __restrict__ k,
                 const float* __restrict__ v, float* __restrict__ y) {
    int t = blockIdx.x, hh = blockIdx.y, tid = threadIdx.x;
    __shared__ float sc[TT];
    __shared__ float qv[HDD];
    __shared__ float red[256];
    size_t hb = (size_t)hh * HDD;
    if (tid < HDD) qv[tid] = q[(size_t)t * CC + hb + tid];
    __syncthreads();
    int n = t + 1;
    float lmax = -1e30f;
    for (int j = tid; j < n; j += 256) {
        const float* kr = k + (size_t)j * CC + hb;
        float dot = 0.f;
#pragma unroll
        for (int d = 0; d < HDD; d += 4) {
            float4 kv = *(const float4*)(kr + d);
            dot += qv[d] * kv.x + qv[d + 1] * kv.y + qv[d + 2] * kv.z + qv[d + 3] * kv.w;
        }
        dot *= 0.125f;   // 1/sqrt(64)
        sc[j] = dot;
        lmax = fmaxf(lmax, dot);
    }
    red[tid] = lmax; __syncthreads();
    for (int s = 128; s > 0; s >>= 1) {
        if (tid < s) red[tid] = fmaxf(red[tid], red[tid + s]);
        __syncthreads();
    }
    float m = red[0]; __syncthreads();
    float lsum = 0.f;
    for (int j = tid; j < n; j += 256) {
        float p = expf(sc[j] - m);
        sc[j] = p;
        lsum += p;
    }
    red[tid] = lsum; __syncthreads();
    for (int s = 128; s > 0; s >>= 1) {
        if (tid < s) red[tid] += red[tid + s];
        __syncthreads();
    }
    float inv = 1.f / red[0]; __syncthreads();
    int d = tid & 63, g = tid >> 6;
    float acc = 0.f;
    for (int j = g; j < n; j += 4) acc += sc[j] * v[(size_t)j * CC + hb + d];
    red[tid] = acc; __syncthreads();
    if (tid < 64)
        y[(size_t)t * CC + hb + tid] =
            (red[tid] + red[tid + 64] + red[tid + 128] + red[tid + 192]) * inv;
}

// ---------------------------------------------------------------------------
// Router: logits = hn @ router_w, softmax over E=8, top-2, aux-loss stats.
__global__ void router_kernel(const float* __restrict__ hn,
                              const float* __restrict__ rw,
                              int* topi, float* topp,
                              int* cnt, float* psum, float* argc) {
    int t = blockIdx.x, lane = threadIdx.x;
    float acc[EE] = {};
    const float* xr = hn + (size_t)t * CC;
    for (int c = lane; c < CC; c += 64) {
        float xv = xr[c];
        const float* rr = rw + (size_t)c * EE;
#pragma unroll
        for (int e = 0; e < EE; e++) acc[e] += xv * rr[e];
    }
#pragma unroll
    for (int e = 0; e < EE; e++)
        for (int off = 32; off > 0; off >>= 1) acc[e] += __shfl_down(acc[e], off);
    if (lane == 0) {
        float m = acc[0];
        for (int e = 1; e < EE; e++) m = fmaxf(m, acc[e]);
        float p[EE], s = 0.f;
        for (int e = 0; e < EE; e++) { p[e] = expf(acc[e] - m); s += p[e]; }
        for (int e = 0; e < EE; e++) p[e] /= s;
        int i0 = 0;
        for (int e = 1; e < EE; e++) if (p[e] > p[i0]) i0 = e;
        int i1 = (i0 == 0) ? 1 : 0;
        for (int e = 0; e < EE; e++) if (e != i0 && p[e] > p[i1]) i1 = e;
        float s2 = p[i0] + p[i1];
        topi[t * 2] = i0; topi[t * 2 + 1] = i1;
        topp[t * 2] = p[i0] / s2; topp[t * 2 + 1] = p[i1] / s2;
        atomicAdd(&cnt[i0], 1); atomicAdd(&cnt[i1], 1);
        atomicAdd(&argc[i0], 1.0f);
        for (int e = 0; e < EE; e++) atomicAdd(&psum[e], p[e]);
    }
}

// ---------------------------------------------------------------------------
// Per-expert padded offsets (64-aligned), cursors, and aux loss.
__global__ void offsets_kernel(const int* cnt, int* offs, int* cursor,
                               const float* psum, const float* argc, float* out) {
    if (threadIdx.x == 0 && blockIdx.x == 0) {
        int o = 0;
        for (int e = 0; e < EE; e++) {
            offs[e] = o; cursor[e] = o;
            o += ((cnt[e] + 63) >> 6) << 6;
        }
        offs[EE] = o;
        float fp = 0.f;
        for (int e = 0; e < EE; e++)
            fp += (argc[e] * (1.f / TT)) * (psum[e] * (1.f / TT));
        out[(size_t)TT * CC] = 0.01f * (float)EE * fp;
    }
}

// ---------------------------------------------------------------------------
// Scatter token-expert pairs into per-expert contiguous row lists.
__global__ void scatter_kernel(const int* topi, const float* topp, int* cursor,
                               int* rowtok, float* roww) {
    int g = blockIdx.x * 256 + threadIdx.x;
    if (g >= TT * 2) return;
    int e = topi[g];
    int r = atomicAdd(&cursor[e], 1);
    rowtok[r] = g >> 1;
    roww[r] = topp[g];
}

// ---------------------------------------------------------------------------
__global__ void copy_kernel(const float* __restrict__ h, float* __restrict__ out) {
    size_t g = (size_t)blockIdx.x * 256 + threadIdx.x;
    out[g] = h[g];
}

// ---------------------------------------------------------------------------
// MoE up-projection: gathered rows of hn @ (w1[e], w2[e]) -> silu(h1)*h2
__global__ __launch_bounds__(256)
void moe_up_kernel(const float* __restrict__ xn, const float* __restrict__ w1,
                   const float* __restrict__ w2, const int* __restrict__ offs,
                   const int* __restrict__ rowtok, float* __restrict__ hid) {
    int row0 = blockIdx.x * 64, n0 = blockIdx.y * 64;
    if (row0 >= offs[EE]) return;
    int e = 0;
#pragma unroll
    for (int ee = 0; ee < EE; ee++) if (row0 >= offs[ee + 1]) e = ee + 1;
    const float* B1 = w1 + (size_t)e * CC * HIDD;
    const float* B2 = w2 + (size_t)e * CC * HIDD;
    __shared__ float As[16][65];
    __shared__ float B1s[16][64];
    __shared__ float B2s[16][64];
    int tid = threadIdx.x;
    int ai = tid >> 2, ak4 = (tid & 3) * 4;
    int bk = tid >> 4, bj4 = (tid & 15) * 4;
    int ty = tid >> 4, tx = tid & 15;
    int atok = rowtok[row0 + ai];
    const float* arow = (atok >= 0) ? (xn + (size_t)atok * CC) : nullptr;
    float acc1[4][4] = {}, acc2[4][4] = {};
    for (int k0 = 0; k0 < CC; k0 += 16) {
        float4 av = arow ? *(const float4*)(arow + k0 + ak4) : make_float4(0, 0, 0, 0);
        As[ak4 + 0][ai] = av.x; As[ak4 + 1][ai] = av.y;
        As[ak4 + 2][ai] = av.z; As[ak4 + 3][ai] = av.w;
        *(float4*)&B1s[bk][bj4] = *(const float4*)(B1 + (size_t)(k0 + bk) * HIDD + n0 + bj4);
        *(float4*)&B2s[bk][bj4] = *(const float4*)(B2 + (size_t)(k0 + bk) * HIDD + n0 + bj4);
        __syncthreads();
#pragma unroll
        for (int kk = 0; kk < 16; kk++) {
            float a[4], b1[4], b2[4];
#pragma unroll
            for (int r = 0; r < 4; r++) a[r] = As[kk][ty * 4 + r];
#pragma unroll
            for (int c = 0; c < 4; c++) { b1[c] = B1s[kk][tx * 4 + c]; b2[c] = B2s[kk][tx * 4 + c]; }
#pragma unroll
            for (int r = 0; r < 4; r++)
#pragma unroll
                for (int c = 0; c < 4; c++) {
                    acc1[r][c] += a[r] * b1[c];
                    acc2[r][c] += a[r] * b2[c];
                }
        }
        __syncthreads();
    }
#pragma unroll
    for (int r = 0; r < 4; r++) {
        size_t row = row0 + ty * 4 + r;
#pragma unroll
        for (int c = 0; c < 4; c++) {
            float h1 = acc1[r][c], h2 = acc2[r][c];
            float sv = h1 / (1.f + expf(-h1));   // silu
            hid[row * HIDD + n0 + tx * 4 + c] = sv * h2;
        }
    }
}

// ---------------------------------------------------------------------------
// MoE down-projection: hid @ w3[e], weighted scatter-add into output.
__global__ __launch_bounds__(256)
void moe_down_kernel(const float* __restrict__ hid, const float* __restrict__ w3,
                     const int* __restrict__ offs, const int* __restrict__ rowtok,
                     const float* __restrict__ roww, float* __restrict__ out) {
    int row0 = blockIdx.x * 64, n0 = blockIdx.y * 64;
    if (row0 >= offs[EE]) return;
    int e = 0;
#pragma unroll
    for (int ee = 0; ee < EE; ee++) if (row0 >= offs[ee + 1]) e = ee + 1;
    const float* B3 = w3 + (size_t)e * HIDD * CC;
    __shared__ float As[16][65];
    __shared__ float Bs[16][64];
    int tid = threadIdx.x;
    int ai = tid >> 2, ak4 = (tid & 3) * 4;
    int bk = tid >> 4, bj4 = (tid & 15) * 4;
    int ty = tid >> 4, tx = tid & 15;
    const float* arow = hid + (size_t)(row0 + ai) * HIDD;
    float acc[4][4] = {};
    for (int k0 = 0; k0 < HIDD; k0 += 16) {
        float4 av = *(const float4*)(arow + k0 + ak4);
        As[ak4 + 0][ai] = av.x; As[ak4 + 1][ai] = av.y;
        As[ak4 + 2][ai] = av.z; As[ak4 + 3][ai] = av.w;
        *(float4*)&Bs[bk][bj4] = *(const float4*)(B3 + (size_t)(k0 + bk) * CC + n0 + bj4);
        __syncthreads();
#pragma unroll
        for (int kk = 0; kk < 16; kk++) {
            float a[4], b[4];
#pragma unroll
            for (int r = 0; r < 4; r++) a[r] = As[kk][ty * 4 + r];
#pragma unroll
            for (int c = 0; c < 4; c++) b[c] = Bs[kk][tx * 4 + c];
#pragma unroll
            for (int r = 0; r < 4; r++)
#pragma unroll
                for (int c = 0; c < 4; c++) acc[r][c] += a[r] * b[c];
        }
        __syncthreads();
    }
#pragma unroll
    for (int r = 0; r < 4; r++) {
        int row = row0 + ty * 4 + r;
        int tk = rowtok[row];
        if (tk < 0) continue;
        float wgt = roww[row];
#pragma unroll
        for (int c = 0; c < 4; c++)
            atomicAdd(&out[(size_t)tk * CC + n0 + tx * 4 + c], wgt * acc[r][c]);
    }
}

// ---------------------------------------------------------------------------
extern "C" void kernel_launch(void* const* d_in, const int* in_sizes, int n_in,
                              void* d_out, int out_size, void* d_ws, size_t ws_size,
                              hipStream_t stream) {
    const float* x           = (const float*)d_in[0];
    const float* attn_norm_w = (const float*)d_in[1];
    const float* wq          = (const float*)d_in[2];
    const float* wk          = (const float*)d_in[3];
    const float* wv          = (const float*)d_in[4];
    const float* wo          = (const float*)d_in[5];
    const float* mlp_norm_w  = (const float*)d_in[6];
    const float* router_w    = (const float*)d_in[7];
    const float* w1          = (const float*)d_in[8];
    const float* w2          = (const float*)d_in[9];
    const float* w3          = (const float*)d_in[10];
    float* out = (float*)d_out;
    float* ws  = (float*)d_ws;

    size_t o = 0;
    float* xn   = ws + o; o += (size_t)TT * CC;   // reused as hn after attention
    float* q    = ws + o; o += (size_t)TT * CC;
    float* kbuf = ws + o; o += (size_t)TT * CC;
    float* vbuf = ws + o; o += (size_t)TT * CC;
    float* y    = ws + o; o += (size_t)TT * CC;
    float* h    = ws + o; o += (size_t)TT * CC;
    float* topp = ws + o; o += TT * 2;
    float* roww = ws + o; o += ROWCAP;
    float* psum = ws + o; o += EE;
    float* argc = ws + o; o += EE;
    int* topi   = (int*)(ws + o);
    int* cnt    = topi + TT * 2;
    int* offs   = cnt + EE;
    int* cursor = offs + EE + 1;
    int* rowtok = cursor + EE;
    o += TT * 2 + EE + (EE + 1) + EE + ROWCAP;
    o = (o + 3) & ~(size_t)3;                     // 16B-align for float4
    float* hid = ws + o; o += (size_t)ROWCAP * HIDD;

    init_kernel<<<(ROWCAP + 255) / 256, 256, 0, stream>>>(rowtok, cnt, psum, argc);
    rmsnorm_kernel<<<TT, 256, 0, stream>>>(x, attn_norm_w, xn);

    dim3 gq(TT / 64, CC / 64);
    gemm64<<<gq, 256, 0, stream>>>(xn, wq, q,    nullptr, TT, CC, CC);
    gemm64<<<gq, 256, 0, stream>>>(xn, wk, kbuf, nullptr, TT, CC, CC);
    gemm64<<<gq, 256, 0, stream>>>(xn, wv, vbuf, nullptr, TT, CC, CC);

    rope_kernel<<<TT * NHH / 2, 64, 0, stream>>>(q);
    rope_kernel<<<TT * NHH / 2, 64, 0, stream>>>(kbuf);

    dim3 ga(TT, NHH);
    attn_kernel<<<ga, 256, 0, stream>>>(q, kbuf, vbuf, y);

    gemm64<<<gq, 256, 0, stream>>>(y, wo, h, x, TT, CC, CC);   // h = x + y@wo
    rmsnorm_kernel<<<TT, 256, 0, stream>>>(h, mlp_norm_w, xn); // xn := hn

    router_kernel<<<TT, 64, 0, stream>>>(xn, router_w, topi, topp, cnt, psum, argc);
    offsets_kernel<<<1, 1, 0, stream>>>(cnt, offs, cursor, psum, argc, out);
    scatter_kernel<<<(TT * 2 + 255) / 256, 256, 0, stream>>>(topi, topp, cursor, rowtok, roww);
    copy_kernel<<<TT * CC / 256, 256, 0, stream>>>(h, out);    // residual base

    dim3 gu(ROWCAP / 64, HIDD / 64);
    moe_up_kernel<<<gu, 256, 0, stream>>>(xn, w1, w2, offs, rowtok, hid);
    dim3 gd(ROWCAP / 64, CC / 64);
    moe_down_kernel<<<gd, 256, 0, stream>>>(hid, w3, offs, rowtok, roww, out);
}

// Round 4
// 2812.226 us; speedup vs baseline: 1.4918x; 1.4918x over previous
//
#include <hip/hip_runtime.h>
#include <hip/hip_bf16.h>
#include <cstdint>

#define TT   2048
#define CC   1024
#define NHH  16
#define HDD  64
#define EE   8
#define HIDD 4096
#define ROWCAP 5120   // 4096 token-expert rows + 8*128 padding, multiple of 128
#define EPSF 1e-6f

typedef __attribute__((ext_vector_type(8))) short  s16x8;
typedef __attribute__((ext_vector_type(4))) float  f32x4;

static __device__ __forceinline__ unsigned short f2bf(float f) {
    union { float f; unsigned u; } a; a.f = f;
    unsigned r = a.u + 0x7FFFu + ((a.u >> 16) & 1u);   // RNE
    return (unsigned short)(r >> 16);
}
static __device__ __forceinline__ float bf2f(unsigned short s) {
    union { unsigned u; float f; } a; a.u = ((unsigned)s) << 16;
    return a.f;
}
static __device__ __forceinline__ void split_bf(float f, unsigned short& hi,
                                                unsigned short& lo) {
    hi = f2bf(f);
    lo = f2bf(f - bf2f(hi));
}

// ---------------------------------------------------------------------------
__global__ void init_kernel(int* rowtok, int* cnt, float* psum, float* argc) {
    int g = blockIdx.x * 256 + threadIdx.x;
    if (g < ROWCAP) rowtok[g] = -1;
    if (g < EE) { cnt[g] = 0; psum[g] = 0.f; argc[g] = 0.f; }
}

// ---------------------------------------------------------------------------
__global__ void rmsnorm_kernel(const float* __restrict__ x,
                               const float* __restrict__ w,
                               float* __restrict__ outf,
                               unsigned short* __restrict__ outb) {
    int t = blockIdx.x, tid = threadIdx.x;
    __shared__ float red[256];
    const float* xr = x + (size_t)t * CC;
    float ss = 0.f;
    for (int c = tid; c < CC; c += 256) { float v = xr[c]; ss += v * v; }
    red[tid] = ss; __syncthreads();
    for (int s = 128; s > 0; s >>= 1) {
        if (tid < s) red[tid] += red[tid + s];
        __syncthreads();
    }
    float inv = rsqrtf(red[0] * (1.0f / CC) + EPSF);
    for (int c = tid; c < CC; c += 256) {
        float v = xr[c] * inv * w[c];
        if (outf) outf[(size_t)t * CC + c] = v;
        if (outb) outb[(size_t)t * CC + c] = f2bf(v);
    }
}

// ---------------------------------------------------------------------------
// Near-fp32 MFMA GEMM via split-bf16 (hi+lo), 128x128 tile, BK=32, 4 waves.
// A fp32 [rows x K], B fp32 [K x N] (transposed+split into LDS). N==1024.
// MODE 0: fused QKV (blockIdx.y: 0-7 wq, 8-15 wk, 16-23 wv)
// MODE 1: proj, O0 = acc + res
template<int MODE>
__global__ __launch_bounds__(256)
void gemm_precise(const float* __restrict__ A,
                  const float* __restrict__ B0, const float* __restrict__ B1,
                  const float* __restrict__ B2,
                  float* __restrict__ O0, float* __restrict__ O1,
                  float* __restrict__ O2,
                  const float* __restrict__ res, int K) {
    const int N = 1024;
    int row0 = blockIdx.x * 128;
    int n0; const float* Bp; int mat = 0;
    if (MODE == 0) {
        mat = blockIdx.y >> 3;
        n0 = (blockIdx.y & 7) * 128;
        Bp = (mat == 0) ? B0 : (mat == 1 ? B1 : B2);
    } else {
        n0 = blockIdx.y * 128;
        Bp = B0;
    }

    __shared__ unsigned short AsH[128 * 40], AsL[128 * 40];
    __shared__ unsigned short BsH[128 * 40], BsL[128 * 40];

    int tid = threadIdx.x, lane = tid & 63, wave = tid >> 6;
    int wm = (wave & 1) * 64, wn = (wave >> 1) * 64;
    int l15 = lane & 15, q4 = lane >> 4;
    const unsigned short* aRdH = AsH + (wm + l15) * 40 + q4 * 8;
    const unsigned short* aRdL = AsL + (wm + l15) * 40 + q4 * 8;
    const unsigned short* bRdH = BsH + (wn + l15) * 40 + q4 * 8;
    const unsigned short* bRdL = BsL + (wn + l15) * 40 + q4 * 8;

    int am = tid & 127, aoff = (tid >> 7) * 16;
    int bn = tid & 127, bk2 = (tid >> 7) * 2;
    const float* arow = A + (size_t)(row0 + am) * K;
    const float* bcol = Bp + n0 + bn;
    int awr = am * 40 + aoff;

    f32x4 acc[4][4];
    const f32x4 z4 = {0.f, 0.f, 0.f, 0.f};
#pragma unroll
    for (int mi = 0; mi < 4; mi++)
#pragma unroll
        for (int ni = 0; ni < 4; ni++) acc[mi][ni] = z4;

    for (int k0 = 0; k0 < K; k0 += 32) {
        __syncthreads();
        // stage A: 16 fp32 -> hi/lo bf16
        float av[16];
        *(f32x4*)&av[0]  = *(const f32x4*)(arow + k0 + aoff);
        *(f32x4*)&av[4]  = *(const f32x4*)(arow + k0 + aoff + 4);
        *(f32x4*)&av[8]  = *(const f32x4*)(arow + k0 + aoff + 8);
        *(f32x4*)&av[12] = *(const f32x4*)(arow + k0 + aoff + 12);
        s16x8 h0, h1, l0, l1;
#pragma unroll
        for (int i = 0; i < 8; i++) {
            unsigned short h, l;
            split_bf(av[i], h, l); h0[i] = (short)h; l0[i] = (short)l;
            split_bf(av[i + 8], h, l); h1[i] = (short)h; l1[i] = (short)l;
        }
        *(s16x8*)(AsH + awr) = h0; *(s16x8*)(AsH + awr + 8) = h1;
        *(s16x8*)(AsL + awr) = l0; *(s16x8*)(AsL + awr + 8) = l1;
        // stage B: fp32 -> hi/lo bf16, transposed (Bs[n][k]), k-pairs b32
        const float* bc = bcol + (size_t)k0 * N;
#pragma unroll
        for (int it = 0; it < 8; it++) {
            int k = it * 4 + bk2;
            float v0 = bc[(size_t)k * N];
            float v1 = bc[(size_t)(k + 1) * N];
            unsigned short ha, la, hb, lb;
            split_bf(v0, ha, la); split_bf(v1, hb, lb);
            *(unsigned int*)(BsH + bn * 40 + k) =
                (unsigned int)ha | ((unsigned int)hb << 16);
            *(unsigned int*)(BsL + bn * 40 + k) =
                (unsigned int)la | ((unsigned int)lb << 16);
        }
        __syncthreads();
        s16x8 aH[4], aL[4], bH[4], bL[4];
#pragma unroll
        for (int mi = 0; mi < 4; mi++) {
            aH[mi] = *(const s16x8*)(aRdH + mi * 640);
            aL[mi] = *(const s16x8*)(aRdL + mi * 640);
        }
#pragma unroll
        for (int ni = 0; ni < 4; ni++) {
            bH[ni] = *(const s16x8*)(bRdH + ni * 640);
            bL[ni] = *(const s16x8*)(bRdL + ni * 640);
        }
#pragma unroll
        for (int mi = 0; mi < 4; mi++)
#pragma unroll
            for (int ni = 0; ni < 4; ni++) {
                acc[mi][ni] = __builtin_amdgcn_mfma_f32_16x16x32_bf16(
                    aH[mi], bH[ni], acc[mi][ni], 0, 0, 0);
                acc[mi][ni] = __builtin_amdgcn_mfma_f32_16x16x32_bf16(
                    aH[mi], bL[ni], acc[mi][ni], 0, 0, 0);
                acc[mi][ni] = __builtin_amdgcn_mfma_f32_16x16x32_bf16(
                    aL[mi], bH[ni], acc[mi][ni], 0, 0, 0);
                acc[mi][ni] = __builtin_amdgcn_mfma_f32_16x16x32_bf16(
                    aL[mi], bL[ni], acc[mi][ni], 0, 0, 0);
            }
    }

    // C/D layout: col=lane&15, row=(lane>>4)*4+reg  [m89-verified]
#pragma unroll
    for (int mi = 0; mi < 4; mi++)
#pragma unroll
        for (int r = 0; r < 4; r++) {
            int gm = row0 + wm + mi * 16 + q4 * 4 + r;
#pragma unroll
            for (int ni = 0; ni < 4; ni++) {
                int gn = n0 + wn + ni * 16 + l15;
                float v = acc[mi][ni][r];
                size_t idx = (size_t)gm * 1024 + gn;
                if (MODE == 0) {
                    float* Od = (mat == 0) ? O0 : (mat == 1 ? O1 : O2);
                    Od[idx] = v;
                } else {
                    O0[idx] = v + res[idx];
                }
            }
        }
}

// ---------------------------------------------------------------------------
// Fast bf16 MFMA GEMM for MoE (output-only path, tolerance-covered).
// Expert row ranges are 128-aligned (offsets_kernel) so each 128-row tile
// belongs to exactly one expert.  // R3 bug: 64-aligned offsets + 128 tiles
// MODE 2: MoE up, gathered A rows via rowtok, per-expert B, bf16 out
// MODE 3: MoE down, direct A rows, per-expert B, weighted atomicAdd into O0
template<int MODE>
__global__ __launch_bounds__(256)
void gemm_bf16(const unsigned short* __restrict__ A,
               const float* __restrict__ B0,
               float* __restrict__ O0, unsigned short* __restrict__ Obf,
               const int* __restrict__ offs, const int* __restrict__ rowtok,
               const float* __restrict__ roww, int K, int N) {
    int row0 = blockIdx.x * 128;
    int n0 = blockIdx.y * 128;
    int total = offs[EE];
    if (row0 >= total) return;
    int e = 0;
#pragma unroll
    for (int ee = 0; ee < EE; ee++) if (row0 >= offs[ee + 1]) e = ee + 1;
    const float* Bp = B0 + (size_t)e * K * N;

    __shared__ unsigned short As[128 * 40];
    __shared__ unsigned short Bs[128 * 40];

    int tid = threadIdx.x, lane = tid & 63, wave = tid >> 6;
    int wm = (wave & 1) * 64, wn = (wave >> 1) * 64;
    int l15 = lane & 15, q4 = lane >> 4;
    const unsigned short* aRd = As + (wm + l15) * 40 + q4 * 8;
    const unsigned short* bRd = Bs + (wn + l15) * 40 + q4 * 8;

    int am = tid & 127, aoff = (tid >> 7) * 16;
    int bn = tid & 127, bk2 = (tid >> 7) * 2;
    const unsigned short* arow;
    if (MODE == 2) {
        int tok = rowtok[row0 + am];
        arow = (tok >= 0) ? (A + (size_t)tok * K) : nullptr;
    } else {
        arow = A + (size_t)(row0 + am) * K;
    }
    unsigned short* aWr = As + am * 40 + aoff;
    const float* bcol = Bp + n0 + bn;

    f32x4 acc[4][4];
    const f32x4 z4 = {0.f, 0.f, 0.f, 0.f};
#pragma unroll
    for (int mi = 0; mi < 4; mi++)
#pragma unroll
        for (int ni = 0; ni < 4; ni++) acc[mi][ni] = z4;
    const s16x8 z8 = {0, 0, 0, 0, 0, 0, 0, 0};

    for (int k0 = 0; k0 < K; k0 += 32) {
        __syncthreads();
        s16x8 av0 = z8, av1 = z8;
        if (arow) {
            av0 = *(const s16x8*)(arow + k0 + aoff);
            av1 = *(const s16x8*)(arow + k0 + aoff + 8);
        }
        *(s16x8*)aWr = av0;
        *(s16x8*)(aWr + 8) = av1;
        const float* bc = bcol + (size_t)k0 * N;
#pragma unroll
        for (int it = 0; it < 8; it++) {
            int k = it * 4 + bk2;
            float v0 = bc[(size_t)k * N];
            float v1 = bc[(size_t)(k + 1) * N];
            *(unsigned int*)(Bs + bn * 40 + k) =
                (unsigned int)f2bf(v0) | ((unsigned int)f2bf(v1) << 16);
        }
        __syncthreads();
        s16x8 af[4], bfr[4];
#pragma unroll
        for (int mi = 0; mi < 4; mi++) af[mi] = *(const s16x8*)(aRd + mi * 640);
#pragma unroll
        for (int ni = 0; ni < 4; ni++) bfr[ni] = *(const s16x8*)(bRd + ni * 640);
#pragma unroll
        for (int mi = 0; mi < 4; mi++)
#pragma unroll
            for (int ni = 0; ni < 4; ni++)
                acc[mi][ni] = __builtin_amdgcn_mfma_f32_16x16x32_bf16(
                    af[mi], bfr[ni], acc[mi][ni], 0, 0, 0);
    }

#pragma unroll
    for (int mi = 0; mi < 4; mi++)
#pragma unroll
        for (int r = 0; r < 4; r++) {
            int gm = row0 + wm + mi * 16 + q4 * 4 + r;
            int tok = 0; float wgt = 0.f;
            if (MODE == 3) {
                tok = rowtok[gm];
                if (tok < 0) continue;
                wgt = roww[gm];
            }
#pragma unroll
            for (int ni = 0; ni < 4; ni++) {
                int gn = n0 + wn + ni * 16 + l15;
                float v = acc[mi][ni][r];
                if (MODE == 2) {
                    Obf[(size_t)gm * 4096 + gn] = f2bf(v);
                } else {
                    atomicAdd(&O0[(size_t)tok * 1024 + gn], wgt * v);
                }
            }
        }
}

// ---------------------------------------------------------------------------
__global__ void rope_kernel(float* buf) {
    int lane = threadIdx.x;
    int fh = blockIdx.x * 2 + (lane >> 5);
    int i = lane & 31;
    int t = fh >> 4;
    size_t base = (size_t)fh * HDD;
    float v0 = buf[base + 2 * i];
    float v1 = buf[base + 2 * i + 1];
    float freq = powf(10000.f, -(float)i / 32.f);
    float ang = (float)t * freq;
    float sn, cs;
    sincosf(ang, &sn, &cs);
    buf[base + i]      = v0 * cs - v1 * sn;
    buf[base + 32 + i] = v0 * sn + v1 * cs;
}

// ---------------------------------------------------------------------------
__global__ __launch_bounds__(256)
void attn_kernel(const float* __restrict__ q, const float* __restrict__ k,
                 const float* __restrict__ v, float* __restrict__ y) {
    int t = blockIdx.x, hh = blockIdx.y, tid = threadIdx.x;
    __shared__ float sc[TT];
    __shared__ float qv[HDD];
    __shared__ float red[256];
    size_t hb = (size_t)hh * HDD;
    if (tid < HDD) qv[tid] = q[(size_t)t * CC + hb + tid];
    __syncthreads();
    int n = t + 1;
    float lmax = -1e30f;
    for (int j = tid; j < n; j += 256) {
        const float* kr = k + (size_t)j * CC + hb;
        float dot = 0.f;
#pragma unroll
        for (int d = 0; d < HDD; d += 4) {
            float4 kv = *(const float4*)(kr + d);
            dot += qv[d] * kv.x + qv[d + 1] * kv.y + qv[d + 2] * kv.z + qv[d + 3] * kv.w;
        }
        dot *= 0.125f;
        sc[j] = dot;
        lmax = fmaxf(lmax, dot);
    }
    red[tid] = lmax; __syncthreads();
    for (int s = 128; s > 0; s >>= 1) {
        if (tid < s) red[tid] = fmaxf(red[tid], red[tid + s]);
        __syncthreads();
    }
    float m = red[0]; __syncthreads();
    float lsum = 0.f;
    for (int j = tid; j < n; j += 256) {
        float p = expf(sc[j] - m);
        sc[j] = p;
        lsum += p;
    }
    red[tid] = lsum; __syncthreads();
    for (int s = 128; s > 0; s >>= 1) {
        if (tid < s) red[tid] += red[tid + s];
        __syncthreads();
    }
    float inv = 1.f / red[0]; __syncthreads();
    int d = tid & 63, g = tid >> 6;
    float acc = 0.f;
    for (int j = g; j < n; j += 4) acc += sc[j] * v[(size_t)j * CC + hb + d];
    red[tid] = acc; __syncthreads();
    if (tid < 64)
        y[(size_t)t * CC + hb + tid] =
            (red[tid] + red[tid + 64] + red[tid + 128] + red[tid + 192]) * inv;
}

// ---------------------------------------------------------------------------
__global__ void router_kernel(const float* __restrict__ hn,
                              const float* __restrict__ rw,
                              int* topi, float* topp,
                              int* cnt, float* psum, float* argc) {
    int t = blockIdx.x, lane = threadIdx.x;
    float acc[EE] = {};
    const float* xr = hn + (size_t)t * CC;
    for (int c = lane; c < CC; c += 64) {
        float xv = xr[c];
        const float* rr = rw + (size_t)c * EE;
#pragma unroll
        for (int e = 0; e < EE; e++) acc[e] += xv * rr[e];
    }
#pragma unroll
    for (int e = 0; e < EE; e++)
        for (int off = 32; off > 0; off >>= 1) acc[e] += __shfl_down(acc[e], off);
    if (lane == 0) {
        float m = acc[0];
        for (int e = 1; e < EE; e++) m = fmaxf(m, acc[e]);
        float p[EE], s = 0.f;
        for (int e = 0; e < EE; e++) { p[e] = expf(acc[e] - m); s += p[e]; }
        for (int e = 0; e < EE; e++) p[e] /= s;
        int i0 = 0;
        for (int e = 1; e < EE; e++) if (p[e] > p[i0]) i0 = e;
        int i1 = (i0 == 0) ? 1 : 0;
        for (int e = 0; e < EE; e++) if (e != i0 && p[e] > p[i1]) i1 = e;
        float s2 = p[i0] + p[i1];
        topi[t * 2] = i0; topi[t * 2 + 1] = i1;
        topp[t * 2] = p[i0] / s2; topp[t * 2 + 1] = p[i1] / s2;
        atomicAdd(&cnt[i0], 1); atomicAdd(&cnt[i1], 1);
        atomicAdd(&argc[i0], 1.0f);
        for (int e = 0; e < EE; e++) atomicAdd(&psum[e], p[e]);
    }
}

// ---------------------------------------------------------------------------
// Per-expert padded offsets (128-aligned to match 128-row GEMM tiles).
__global__ void offsets_kernel(const int* cnt, int* offs, int* cursor,
                               const float* psum, const float* argc, float* out) {
    if (threadIdx.x == 0 && blockIdx.x == 0) {
        int o = 0;
        for (int e = 0; e < EE; e++) {
            offs[e] = o; cursor[e] = o;
            o += ((cnt[e] + 127) >> 7) << 7;
        }
        offs[EE] = o;
        float fp = 0.f;
        for (int e = 0; e < EE; e++)
            fp += (argc[e] * (1.f / TT)) * (psum[e] * (1.f / TT));
        out[(size_t)TT * CC] = 0.01f * (float)EE * fp;
    }
}

// ---------------------------------------------------------------------------
__global__ void scatter_kernel(const int* topi, const float* topp, int* cursor,
                               int* rowtok, float* roww) {
    int g = blockIdx.x * 256 + threadIdx.x;
    if (g >= TT * 2) return;
    int e = topi[g];
    int r = atomicAdd(&cursor[e], 1);
    rowtok[r] = g >> 1;
    roww[r] = topp[g];
}

// ---------------------------------------------------------------------------
__global__ void copy_kernel(const float* __restrict__ h, float* __restrict__ out) {
    size_t g = (size_t)blockIdx.x * 256 + threadIdx.x;
    out[g] = h[g];
}

// ---------------------------------------------------------------------------
__global__ void silu_mul_kernel(unsigned short* __restrict__ hid1,
                                const unsigned short* __restrict__ hid2) {
    size_t g = ((size_t)blockIdx.x * 256 + threadIdx.x) * 8;
    s16x8 a = *(s16x8*)(hid1 + g);
    s16x8 b = *(const s16x8*)(hid2 + g);
    s16x8 o;
#pragma unroll
    for (int i = 0; i < 8; i++) {
        float f1 = bf2f((unsigned short)a[i]);
        float f2 = bf2f((unsigned short)b[i]);
        float sv = f1 / (1.f + expf(-f1));
        o[i] = (short)f2bf(sv * f2);
    }
    *(s16x8*)(hid1 + g) = o;
}

// ---------------------------------------------------------------------------
extern "C" void kernel_launch(void* const* d_in, const int* in_sizes, int n_in,
                              void* d_out, int out_size, void* d_ws, size_t ws_size,
                              hipStream_t stream) {
    const float* x           = (const float*)d_in[0];
    const float* attn_norm_w = (const float*)d_in[1];
    const float* wq          = (const float*)d_in[2];
    const float* wk          = (const float*)d_in[3];
    const float* wv          = (const float*)d_in[4];
    const float* wo          = (const float*)d_in[5];
    const float* mlp_norm_w  = (const float*)d_in[6];
    const float* router_w    = (const float*)d_in[7];
    const float* w1          = (const float*)d_in[8];
    const float* w2          = (const float*)d_in[9];
    const float* w3          = (const float*)d_in[10];
    float* out = (float*)d_out;
    float* ws  = (float*)d_ws;

    const size_t MTC = (size_t)TT * CC;       // 2M
    size_t o = 0;
    float* xn   = ws + o; o += MTC;
    float* q    = ws + o; o += MTC;
    float* kbuf = ws + o; o += MTC;
    float* vbuf = ws + o; o += MTC;
    float* y    = ws + o; o += MTC;
    float* h    = ws + o; o += MTC;
    float* hn   = ws + o; o += MTC;
    unsigned short* hnb  = (unsigned short*)(ws + o); o += MTC / 2;
    unsigned short* hid1 = (unsigned short*)(ws + o); o += (size_t)ROWCAP * HIDD / 2;
    unsigned short* hid2 = (unsigned short*)(ws + o); o += (size_t)ROWCAP * HIDD / 2;
    float* topp = ws + o; o += TT * 2;
    float* roww = ws + o; o += ROWCAP;
    float* psum = ws + o; o += EE;
    float* argc = ws + o; o += EE;
    int* topi   = (int*)(ws + o);
    int* cnt    = topi + TT * 2;
    int* offs   = cnt + EE;
    int* cursor = offs + EE + 1;
    int* rowtok = cursor + EE;

    init_kernel<<<(ROWCAP + 255) / 256, 256, 0, stream>>>(rowtok, cnt, psum, argc);
    rmsnorm_kernel<<<TT, 256, 0, stream>>>(x, attn_norm_w, xn, nullptr);

    // fused QKV, near-fp32 (split-bf16 4-term MFMA)
    gemm_precise<0><<<dim3(TT / 128, 24), 256, 0, stream>>>(
        xn, wq, wk, wv, q, kbuf, vbuf, nullptr, CC);

    rope_kernel<<<TT * NHH / 2, 64, 0, stream>>>(q);
    rope_kernel<<<TT * NHH / 2, 64, 0, stream>>>(kbuf);

    attn_kernel<<<dim3(TT, NHH), 256, 0, stream>>>(q, kbuf, vbuf, y);

    // proj + residual: h = x + y @ wo, near-fp32
    gemm_precise<1><<<dim3(TT / 128, CC / 128), 256, 0, stream>>>(
        y, wo, nullptr, nullptr, h, nullptr, nullptr, x, CC);

    rmsnorm_kernel<<<TT, 256, 0, stream>>>(h, mlp_norm_w, hn, hnb);

    router_kernel<<<TT, 64, 0, stream>>>(hn, router_w, topi, topp, cnt, psum, argc);
    offsets_kernel<<<1, 1, 0, stream>>>(cnt, offs, cursor, psum, argc, out);
    scatter_kernel<<<(TT * 2 + 255) / 256, 256, 0, stream>>>(topi, topp, cursor, rowtok, roww);
    copy_kernel<<<TT * CC / 256, 256, 0, stream>>>(h, out);

    // MoE up (fast bf16): h1 -> hid1, h2 -> hid2
    gemm_bf16<2><<<dim3(ROWCAP / 128, HIDD / 128), 256, 0, stream>>>(
        hnb, w1, nullptr, hid1, offs, rowtok, nullptr, CC, HIDD);
    gemm_bf16<2><<<dim3(ROWCAP / 128, HIDD / 128), 256, 0, stream>>>(
        hnb, w2, nullptr, hid2, offs, rowtok, nullptr, CC, HIDD);
    silu_mul_kernel<<<(size_t)ROWCAP * HIDD / 2048, 256, 0, stream>>>(hid1, hid2);

    // MoE down + weighted scatter-add into out
    gemm_bf16<3><<<dim3(ROWCAP / 128, CC / 128), 256, 0, stream>>>(
        hid1, w3, out, nullptr, offs, rowtok, roww, HIDD, CC);
}